// Round 16
// baseline (164.067 us; speedup 1.0000x reference)
//
#include <hip/hip_runtime.h>
#include <stdint.h>

typedef unsigned short u16;
typedef __bf16 bf16x8 __attribute__((ext_vector_type(8)));
typedef float f32x4 __attribute__((ext_vector_type(4)));

#define DIN 4096
#define DOUT 4096
#define BB 4096
#define KR 256
#define RK 2048  // 2*L*K

__device__ __forceinline__ u16 f2bf(float f) {
    union { float f; unsigned u; } v; v.f = f;
    unsigned r = v.u + 0x7FFFu + ((v.u >> 16) & 1u);
    return (u16)(r >> 16);
}

__device__ __forceinline__ void gl_lds16(const void* g, void* l) {
    __builtin_amdgcn_global_load_lds((const __attribute__((address_space(1))) void*)g,
                                     (__attribute__((address_space(3))) void*)l,
                                     16, 0, 0);
}

// ---- convert f32 -> bf16, 8 elements/thread ----
__global__ __launch_bounds__(256) void cvt_f32_bf16(const float* __restrict__ src,
                                                    u16* __restrict__ dst, int n8) {
    int i = blockIdx.x * blockDim.x + threadIdx.x;
    if (i >= n8) return;
    const float4* s = reinterpret_cast<const float4*>(src) + (size_t)i * 2;
    float4 a = s[0], b = s[1];
    uint4 o;
    o.x = f2bf(a.x) | ((unsigned)f2bf(a.y) << 16);
    o.y = f2bf(a.z) | ((unsigned)f2bf(a.w) << 16);
    o.z = f2bf(b.x) | ((unsigned)f2bf(b.y) << 16);
    o.w = f2bf(b.z) | ((unsigned)f2bf(b.w) << 16);
    reinterpret_cast<uint4*>(dst)[i] = o;
}

// ---- pack W1T[r][d] = (br? U2s : S1s)[l][d][k], r = l*512 + br*256 + k ----
__global__ __launch_bounds__(256) void pack_w1t(const float* __restrict__ S1s,
                                                const float* __restrict__ U2s,
                                                u16* __restrict__ W1T) {
    __shared__ u16 lds[64][68];
    int b  = blockIdx.x;
    int bd = b & 63;
    int bk = (b >> 6) & 3;
    int lb = b >> 8;
    int l = lb >> 1, br = lb & 1;
    const float* src = (br ? U2s : S1s) + (size_t)l * DIN * KR;
    int t = threadIdx.x;
    int d0 = bd * 64, k0 = bk * 64;
    int r0 = l * 512 + br * 256 + k0;
    #pragma unroll
    for (int p = 0; p < 4; ++p) {
        int dl = p * 16 + (t >> 4);
        int kc = (t & 15) * 4;
        float4 v = *reinterpret_cast<const float4*>(src + (size_t)(d0 + dl) * KR + k0 + kc);
        ushort4 pk;
        pk.x = f2bf(v.x); pk.y = f2bf(v.y); pk.z = f2bf(v.z); pk.w = f2bf(v.w);
        *reinterpret_cast<ushort4*>(&lds[dl][kc]) = pk;
    }
    __syncthreads();
    #pragma unroll
    for (int p = 0; p < 2; ++p) {
        int kl = p * 32 + (t >> 3);
        int d8 = t & 7;
        u16 tmp[8];
        #pragma unroll
        for (int j = 0; j < 8; ++j) tmp[j] = lds[d8 * 8 + j][kl];
        uint4 o;
        o.x = tmp[0] | ((unsigned)tmp[1] << 16);
        o.y = tmp[2] | ((unsigned)tmp[3] << 16);
        o.z = tmp[4] | ((unsigned)tmp[5] << 16);
        o.w = tmp[6] | ((unsigned)tmp[7] << 16);
        *reinterpret_cast<uint4*>(W1T + (size_t)(r0 + kl) * DIN + d0 + d8 * 8) = o;
    }
}

// ---- pack W2T[o][r] = (br? S2s : U1s)[l][k][o] ----
__global__ __launch_bounds__(256) void pack_w2t(const float* __restrict__ U1s,
                                                const float* __restrict__ S2s,
                                                u16* __restrict__ W2T) {
    __shared__ u16 lds[64][68];
    int b  = blockIdx.x;
    int bo = b & 63;
    int bk = (b >> 6) & 3;
    int lb = b >> 8;
    int l = lb >> 1, br = lb & 1;
    const float* src = (br ? S2s : U1s) + (size_t)l * KR * DOUT;
    int t = threadIdx.x;
    int o0 = bo * 64, k0 = bk * 64;
    #pragma unroll
    for (int p = 0; p < 4; ++p) {
        int kl = p * 16 + (t >> 4);
        int ol = (t & 15) * 4;
        float4 v = *reinterpret_cast<const float4*>(src + (size_t)(k0 + kl) * DOUT + o0 + ol);
        ushort4 pk;
        pk.x = f2bf(v.x); pk.y = f2bf(v.y); pk.z = f2bf(v.z); pk.w = f2bf(v.w);
        *reinterpret_cast<ushort4*>(&lds[kl][ol]) = pk;
    }
    __syncthreads();
    #pragma unroll
    for (int p = 0; p < 2; ++p) {
        int ol = p * 32 + (t >> 3);
        int k8 = t & 7;
        u16 tmp[8];
        #pragma unroll
        for (int j = 0; j < 8; ++j) tmp[j] = lds[k8 * 8 + j][ol];
        uint4 o;
        o.x = tmp[0] | ((unsigned)tmp[1] << 16);
        o.y = tmp[2] | ((unsigned)tmp[3] << 16);
        o.z = tmp[4] | ((unsigned)tmp[5] << 16);
        o.w = tmp[6] | ((unsigned)tmp[7] << 16);
        *reinterpret_cast<uint4*>(W2T + (size_t)(o0 + ol) * RK + l * 512 + br * 256 + k0 + k8 * 8) = o;
    }
}

// ==== 8-phase pipelined 256xBN GEMM: C = A[M][KD] * Bt[ND][KD]^T ====
// r15 champion structure (PIPE=2, 2 barriers/iter at p3/p7, vmcnt(4|3)
// gates, single A-set reload-after-last-use, swizzled LDS, XCD swizzle)
// with setprio REMOVED from the MFMA bursts: T5 is gated on the 8-phase
// burst schedule (m218b); on compiler-interleaved structures it is
// measured NEGATIVE (m190) — a prio-1 wave's MFMA burst starves the
// co-SIMD wave's ds_read issue, serializing the LDS pipe (our measured
// dead time, worse for GEMM2's 16-MFMA bursts than GEMM1's 8).
// Hazard ledgers (WAR slot-by-slot, RAW vmcnt drains for steady/J0/
// prologue) unchanged from r15 and re-verified.
template <int BN, int MW, int EPI, int ND, int KD>
__global__ __launch_bounds__(512)
__attribute__((amdgpu_waves_per_eu(2, 2)))
void gemm8(const u16* __restrict__ A,
           const u16* __restrict__ Bt,
           void* __restrict__ Cv,
           const float* __restrict__ bias) {
    extern __shared__ char smem[];
    constexpr int BHB = (BN == 256) ? 16384 : 8192;  // B half bytes
    constexpr int BROWS = BN / 2;                    // B half rows
    constexpr int NW = 8 / MW;
    constexpr int MF = 128 / (16 * MW);
    constexpr int MROW = 128 / MW;
    char* ldsA = smem;                // 4 halves * 16KB
    char* ldsB = smem + 65536;        // 4 halves * BHB

    const int tid = threadIdx.x;
    const int l = tid & 63;
    const int wv = tid >> 6;
    const int wr = wv / NW;
    const int wc = wv % NW;

    int bid = blockIdx.x;            // 256 blocks always
    bid = (bid & 7) * 32 + (bid >> 3);   // bijective XCD swizzle (256%8==0)
    const int mt = bid >> 4, nt = bid & 15;
    const int m0 = mt * 256, n0 = nt * BN;

    constexpr int NITER = KD >> 7;

    // staging per-thread source offsets, 32-bit (swizzle pre-applied)
    unsigned aoff[2], boff[2];
    {
        #pragma unroll
        for (int r = 0; r < 2; ++r) {
            int lin = (r * 512 + tid) * 16;
            int s = lin ^ (((lin >> 7) & 7) << 4);
            int e = s >> 1;
            unsigned o = (unsigned)(e >> 6) * (unsigned)KD + (unsigned)(e & 63);
            aoff[r] = (unsigned)m0 * (unsigned)KD + o;
            boff[r] = (unsigned)n0 * (unsigned)KD + o;
        }
    }

    auto issueA = [&](int h, int b, unsigned kb) {
        char* d = ldsA + (((b << 1) | h) * 16384) + tid * 16;
        gl_lds16(A + aoff[0] + (unsigned)h * 128u * KD + kb, d);
        gl_lds16(A + aoff[1] + (unsigned)h * 128u * KD + kb, d + 8192);
    };
    auto issueB = [&](int h, int b, unsigned kb) {
        char* d = ldsB + (((b << 1) | h) * BHB) + tid * 16;
        gl_lds16(Bt + boff[0] + (unsigned)h * (unsigned)BROWS * KD + kb, d);
        if constexpr (BN == 256)
            gl_lds16(Bt + boff[1] + (unsigned)h * (unsigned)BROWS * KD + kb, d + 8192);
    };

    // LDS read addr = rowAb[m] (swizzle cc0 pre-folded; second k-slice: ^64)
    const int cc0 = ((l >> 4) ^ (l & 7)) << 4;
    int rowAb[MF];
    #pragma unroll
    for (int m = 0; m < MF; ++m) rowAb[m] = ((wr * MROW + m * 16 + (l & 15)) * 128) | cc0;
    int rowBb[2];
    #pragma unroll
    for (int n = 0; n < 2; ++n) rowBb[n] = ((wc * 32 + n * 16 + (l & 15)) * 128) | cc0;

    f32x4 acc[2][2][MF][2] = {};
    bf16x8 afA[MF][2];               // single A-set (reload after last use)
    bf16x8 bf0[2][2], bf1[2][2];     // B-frag slots (nh=0 / nh=1)

#define RDA(B_, H_) do { const char* Ah_ = ldsA + (((B_) << 1) | (H_)) * 16384;       \
    _Pragma("unroll") for (int m_ = 0; m_ < MF; ++m_) {                               \
        afA[m_][0] = *(const bf16x8*)(Ah_ + rowAb[m_]);                               \
        afA[m_][1] = *(const bf16x8*)(Ah_ + (rowAb[m_] ^ 64)); } } while (0)
#define RDB(DST, B_, H_) do { const char* Bh_ = ldsB + (((B_) << 1) | (H_)) * BHB;    \
    _Pragma("unroll") for (int n_ = 0; n_ < 2; ++n_) {                                \
        DST[n_][0] = *(const bf16x8*)(Bh_ + rowBb[n_]);                               \
        DST[n_][1] = *(const bf16x8*)(Bh_ + (rowBb[n_] ^ 64)); } } while (0)
#define MM(MH, NH, BREG) do {                                                         \
    _Pragma("unroll") for (int m_ = 0; m_ < MF; ++m_)                                 \
        _Pragma("unroll") for (int n_ = 0; n_ < 2; ++n_) {                            \
            acc[MH][NH][m_][n_] = __builtin_amdgcn_mfma_f32_16x16x32_bf16(            \
                afA[m_][0], BREG[n_][0], acc[MH][NH][m_][n_], 0, 0, 0);               \
            acc[MH][NH][m_][n_] = __builtin_amdgcn_mfma_f32_16x16x32_bf16(            \
                afA[m_][1], BREG[n_][1], acc[MH][NH][m_][n_], 0, 0, 0); }             \
    } while (0)
#define VMW do { if constexpr (BN == 256)                                             \
                     asm volatile("s_waitcnt vmcnt(4)" ::: "memory");                 \
                 else asm volatile("s_waitcnt vmcnt(3)" ::: "memory"); } while (0)
#define FEN asm volatile("" ::: "memory")
#define ENDP do { asm volatile("" ::: "memory");                                      \
                  __builtin_amdgcn_s_barrier(); } while (0)

    // ---- prologue: 6 slots (buf0 full + buf1 half0); gate leaves buf1-half0 in flight
    issueA(0, 0, 0);  issueB(0, 0, 0);
    issueA(1, 0, 0);  issueB(1, 0, 0);
    issueA(0, 1, 64); issueB(0, 1, 64);
    VMW;
    __builtin_amdgcn_s_barrier();

    // ---- PIPE=2, 2 barriers/iter (p3-end, p7-end) ----
    RDA(0, 0); RDB(bf0, 0, 0);
    for (int J = 0; J < NITER; ++J) {
        const unsigned kc = ((unsigned)J << 7);
        // region [p0..p3]
        issueA(1, 1, kc + 64); RDB(bf1, 0, 1); MM(0, 0, bf0);
        issueB(1, 1, kc + 64); MM(0, 1, bf1); RDA(0, 1); FEN;
        issueA(0, 0, kc + 128); MM(1, 1, bf1);
        issueB(0, 0, kc + 128); MM(1, 0, bf0); VMW; RDA(1, 0); RDB(bf0, 1, 0); ENDP;
        // region [p4..p7]
        issueA(1, 0, kc + 128); RDB(bf1, 1, 1); MM(0, 0, bf0);
        issueB(1, 0, kc + 128); MM(0, 1, bf1); RDA(1, 1); FEN;
        issueA(0, 1, kc + 192); MM(1, 1, bf1);
        issueB(0, 1, kc + 192); MM(1, 0, bf0); VMW; RDA(0, 0); RDB(bf0, 0, 0); ENDP;
    }
#undef RDA
#undef RDB
#undef MM
#undef VMW
#undef FEN
#undef ENDP

    const int colc = l & 15, rb = (l >> 4) * 4;
    #pragma unroll
    for (int mh = 0; mh < 2; ++mh)
    #pragma unroll
    for (int nh = 0; nh < 2; ++nh)
    #pragma unroll
    for (int m = 0; m < MF; ++m)
    #pragma unroll
    for (int n = 0; n < 2; ++n) {
        int c = n0 + nh * (BN / 2) + wc * 32 + n * 16 + colc;
        int r0r = m0 + mh * 128 + wr * MROW + m * 16 + rb;
        if (EPI == 0) {
            u16* Cb = (u16*)Cv;
            #pragma unroll
            for (int j = 0; j < 4; ++j)
                Cb[(size_t)(r0r + j) * ND + c] = f2bf(acc[mh][nh][m][n][j]);
        } else {
            float* Cf = (float*)Cv;
            float bv = bias[c];
            #pragma unroll
            for (int j = 0; j < 4; ++j)
                Cf[(size_t)(r0r + j) * ND + c] = (acc[mh][nh][m][n][j] + bv) * 0.125f;
        }
    }
}

extern "C" void kernel_launch(void* const* d_in, const int* in_sizes, int n_in,
                              void* d_out, int out_size, void* d_ws, size_t ws_size,
                              hipStream_t stream) {
    const float* hin  = (const float*)d_in[0];
    const float* S1s  = (const float*)d_in[1];
    const float* S2s  = (const float*)d_in[2];
    const float* U1s  = (const float*)d_in[3];
    const float* U2s  = (const float*)d_in[4];
    const float* bias = (const float*)d_in[5];
    float* out = (float*)d_out;

    // ws: [hinbf][Wx (W1T then W2T)][abf], each padded 512B for the last
    // iteration's prefetch overread (<=256B past the K extent).
    const size_t SZ_HIN = (size_t)BB * DIN * 2 + 512;
    const size_t SZ_W   = (size_t)RK * DIN * 2 + 512;
    const size_t SZ_A   = (size_t)BB * RK * 2 + 512;
    if (ws_size < SZ_HIN + SZ_W + SZ_A) return;
    u16* hinbf = (u16*)d_ws;
    u16* Wx    = (u16*)((char*)d_ws + SZ_HIN);
    u16* abf   = (u16*)((char*)d_ws + SZ_HIN + SZ_W);

    (void)hipFuncSetAttribute(reinterpret_cast<const void*>(&gemm8<128, 4, 0, RK, DIN>),
                              hipFuncAttributeMaxDynamicSharedMemorySize, 98304);
    (void)hipFuncSetAttribute(reinterpret_cast<const void*>(&gemm8<256, 2, 1, DOUT, RK>),
                              hipFuncAttributeMaxDynamicSharedMemorySize, 131072);

    // 1) pack W1T [RK][DIN]; hin -> bf16
    pack_w1t<<<64 * 4 * 8, 256, 0, stream>>>(S1s, U2s, Wx);
    cvt_f32_bf16<<<(BB * DIN / 8) / 256, 256, 0, stream>>>(hin, hinbf, BB * DIN / 8);
    // 2) a[b][r] = sum_d hin[b][d] * W1T[r][d]   (M=4096, N=2048, K=4096)
    gemm8<128, 4, 0, RK, DIN><<<256, 512, 98304, stream>>>(hinbf, Wx, abf, nullptr);
    // 3) pack W2T [DOUT][RK] (reuses Wx after gemm1)
    pack_w2t<<<64 * 4 * 8, 256, 0, stream>>>(U1s, S2s, Wx);
    // 4) out = (a @ W2T^T + bias) / 8   (M=4096, N=4096, K=2048)
    gemm8<256, 2, 1, DOUT, RK><<<256, 512, 131072, stream>>>(abf, Wx, out, bias);
}

// Round 17
// 162.755 us; speedup vs baseline: 1.0081x; 1.0081x over previous
//
#include <hip/hip_runtime.h>
#include <stdint.h>

typedef unsigned short u16;
typedef __bf16 bf16x8 __attribute__((ext_vector_type(8)));
typedef float f32x4 __attribute__((ext_vector_type(4)));

#define DIN 4096
#define DOUT 4096
#define BB 4096
#define KR 256
#define RK 2048  // 2*L*K

__device__ __forceinline__ u16 f2bf(float f) {
    union { float f; unsigned u; } v; v.f = f;
    unsigned r = v.u + 0x7FFFu + ((v.u >> 16) & 1u);
    return (u16)(r >> 16);
}

__device__ __forceinline__ void gl_lds16(const void* g, void* l) {
    __builtin_amdgcn_global_load_lds((const __attribute__((address_space(1))) void*)g,
                                     (__attribute__((address_space(3))) void*)l,
                                     16, 0, 0);
}

// ---- convert f32 -> bf16, 8 elements/thread ----
__global__ __launch_bounds__(256) void cvt_f32_bf16(const float* __restrict__ src,
                                                    u16* __restrict__ dst, int n8) {
    int i = blockIdx.x * blockDim.x + threadIdx.x;
    if (i >= n8) return;
    const float4* s = reinterpret_cast<const float4*>(src) + (size_t)i * 2;
    float4 a = s[0], b = s[1];
    uint4 o;
    o.x = f2bf(a.x) | ((unsigned)f2bf(a.y) << 16);
    o.y = f2bf(a.z) | ((unsigned)f2bf(a.w) << 16);
    o.z = f2bf(b.x) | ((unsigned)f2bf(b.y) << 16);
    o.w = f2bf(b.z) | ((unsigned)f2bf(b.w) << 16);
    reinterpret_cast<uint4*>(dst)[i] = o;
}

// ---- pack W1T[r][d] = (br? U2s : S1s)[l][d][k], r = l*512 + br*256 + k ----
__global__ __launch_bounds__(256) void pack_w1t(const float* __restrict__ S1s,
                                                const float* __restrict__ U2s,
                                                u16* __restrict__ W1T) {
    __shared__ u16 lds[64][68];
    int b  = blockIdx.x;
    int bd = b & 63;
    int bk = (b >> 6) & 3;
    int lb = b >> 8;
    int l = lb >> 1, br = lb & 1;
    const float* src = (br ? U2s : S1s) + (size_t)l * DIN * KR;
    int t = threadIdx.x;
    int d0 = bd * 64, k0 = bk * 64;
    int r0 = l * 512 + br * 256 + k0;
    #pragma unroll
    for (int p = 0; p < 4; ++p) {
        int dl = p * 16 + (t >> 4);
        int kc = (t & 15) * 4;
        float4 v = *reinterpret_cast<const float4*>(src + (size_t)(d0 + dl) * KR + k0 + kc);
        ushort4 pk;
        pk.x = f2bf(v.x); pk.y = f2bf(v.y); pk.z = f2bf(v.z); pk.w = f2bf(v.w);
        *reinterpret_cast<ushort4*>(&lds[dl][kc]) = pk;
    }
    __syncthreads();
    #pragma unroll
    for (int p = 0; p < 2; ++p) {
        int kl = p * 32 + (t >> 3);
        int d8 = t & 7;
        u16 tmp[8];
        #pragma unroll
        for (int j = 0; j < 8; ++j) tmp[j] = lds[d8 * 8 + j][kl];
        uint4 o;
        o.x = tmp[0] | ((unsigned)tmp[1] << 16);
        o.y = tmp[2] | ((unsigned)tmp[3] << 16);
        o.z = tmp[4] | ((unsigned)tmp[5] << 16);
        o.w = tmp[6] | ((unsigned)tmp[7] << 16);
        *reinterpret_cast<uint4*>(W1T + (size_t)(r0 + kl) * DIN + d0 + d8 * 8) = o;
    }
}

// ---- pack W2T[o][r] = (br? S2s : U1s)[l][k][o] ----
__global__ __launch_bounds__(256) void pack_w2t(const float* __restrict__ U1s,
                                                const float* __restrict__ S2s,
                                                u16* __restrict__ W2T) {
    __shared__ u16 lds[64][68];
    int b  = blockIdx.x;
    int bo = b & 63;
    int bk = (b >> 6) & 3;
    int lb = b >> 8;
    int l = lb >> 1, br = lb & 1;
    const float* src = (br ? S2s : U1s) + (size_t)l * KR * DOUT;
    int t = threadIdx.x;
    int o0 = bo * 64, k0 = bk * 64;
    #pragma unroll
    for (int p = 0; p < 4; ++p) {
        int kl = p * 16 + (t >> 4);
        int ol = (t & 15) * 4;
        float4 v = *reinterpret_cast<const float4*>(src + (size_t)(k0 + kl) * DOUT + o0 + ol);
        ushort4 pk;
        pk.x = f2bf(v.x); pk.y = f2bf(v.y); pk.z = f2bf(v.z); pk.w = f2bf(v.w);
        *reinterpret_cast<ushort4*>(&lds[kl][ol]) = pk;
    }
    __syncthreads();
    #pragma unroll
    for (int p = 0; p < 2; ++p) {
        int ol = p * 32 + (t >> 3);
        int k8 = t & 7;
        u16 tmp[8];
        #pragma unroll
        for (int j = 0; j < 8; ++j) tmp[j] = lds[k8 * 8 + j][ol];
        uint4 o;
        o.x = tmp[0] | ((unsigned)tmp[1] << 16);
        o.y = tmp[2] | ((unsigned)tmp[3] << 16);
        o.z = tmp[4] | ((unsigned)tmp[5] << 16);
        o.w = tmp[6] | ((unsigned)tmp[7] << 16);
        *reinterpret_cast<uint4*>(W2T + (size_t)(o0 + ol) * RK + l * 512 + br * 256 + k0 + k8 * 8) = o;
    }
}

// ==== 8-phase pipelined 256xBN GEMM: C = A[M][KD] * Bt[ND][KD]^T ====
// r15 champion (best measured: 162.9us total): PIPE=2 single-A-set
// reload-after-last-use, 2 barriers/iter (p3/p7 ends), counted vmcnt(4|3)
// gates at p3/p7 (never drained to 0 in-loop), XOR-swizzled LDS
// (conflicts=0), bijective XCD swizzle, setprio(1) around MFMA bursts
// (r16 A/B: removing it cost ~1-3%). Hazard ledgers (WAR slot-by-slot
// under the 2-barrier scheme; RAW vmcnt drains for steady/J0/prologue)
// verified in r14/r15.
// Convergence: GEMM1 at ~88% of its LDS-structural floor, GEMM2 at ~67%
// (+10.6us irreducible f32 C-write); packs/cvt at HBM BW. Six schedule
// variants (r12-r16) all within 163-169us -> this is the plateau of the
// structure; numerics (threshold 0.042) lock out fp8/i8.
template <int BN, int MW, int EPI, int ND, int KD>
__global__ __launch_bounds__(512)
__attribute__((amdgpu_waves_per_eu(2, 2)))
void gemm8(const u16* __restrict__ A,
           const u16* __restrict__ Bt,
           void* __restrict__ Cv,
           const float* __restrict__ bias) {
    extern __shared__ char smem[];
    constexpr int BHB = (BN == 256) ? 16384 : 8192;  // B half bytes
    constexpr int BROWS = BN / 2;                    // B half rows
    constexpr int NW = 8 / MW;
    constexpr int MF = 128 / (16 * MW);
    constexpr int MROW = 128 / MW;
    char* ldsA = smem;                // 4 halves * 16KB
    char* ldsB = smem + 65536;        // 4 halves * BHB

    const int tid = threadIdx.x;
    const int l = tid & 63;
    const int wv = tid >> 6;
    const int wr = wv / NW;
    const int wc = wv % NW;

    int bid = blockIdx.x;            // 256 blocks always
    bid = (bid & 7) * 32 + (bid >> 3);   // bijective XCD swizzle (256%8==0)
    const int mt = bid >> 4, nt = bid & 15;
    const int m0 = mt * 256, n0 = nt * BN;

    constexpr int NITER = KD >> 7;

    // staging per-thread source offsets, 32-bit (swizzle pre-applied)
    unsigned aoff[2], boff[2];
    {
        #pragma unroll
        for (int r = 0; r < 2; ++r) {
            int lin = (r * 512 + tid) * 16;
            int s = lin ^ (((lin >> 7) & 7) << 4);
            int e = s >> 1;
            unsigned o = (unsigned)(e >> 6) * (unsigned)KD + (unsigned)(e & 63);
            aoff[r] = (unsigned)m0 * (unsigned)KD + o;
            boff[r] = (unsigned)n0 * (unsigned)KD + o;
        }
    }

    auto issueA = [&](int h, int b, unsigned kb) {
        char* d = ldsA + (((b << 1) | h) * 16384) + tid * 16;
        gl_lds16(A + aoff[0] + (unsigned)h * 128u * KD + kb, d);
        gl_lds16(A + aoff[1] + (unsigned)h * 128u * KD + kb, d + 8192);
    };
    auto issueB = [&](int h, int b, unsigned kb) {
        char* d = ldsB + (((b << 1) | h) * BHB) + tid * 16;
        gl_lds16(Bt + boff[0] + (unsigned)h * (unsigned)BROWS * KD + kb, d);
        if constexpr (BN == 256)
            gl_lds16(Bt + boff[1] + (unsigned)h * (unsigned)BROWS * KD + kb, d + 8192);
    };

    // LDS read addr = rowAb[m] (swizzle cc0 pre-folded; second k-slice: ^64)
    const int cc0 = ((l >> 4) ^ (l & 7)) << 4;
    int rowAb[MF];
    #pragma unroll
    for (int m = 0; m < MF; ++m) rowAb[m] = ((wr * MROW + m * 16 + (l & 15)) * 128) | cc0;
    int rowBb[2];
    #pragma unroll
    for (int n = 0; n < 2; ++n) rowBb[n] = ((wc * 32 + n * 16 + (l & 15)) * 128) | cc0;

    f32x4 acc[2][2][MF][2] = {};
    bf16x8 afA[MF][2];               // single A-set (reload after last use)
    bf16x8 bf0[2][2], bf1[2][2];     // B-frag slots (nh=0 / nh=1)

#define RDA(B_, H_) do { const char* Ah_ = ldsA + (((B_) << 1) | (H_)) * 16384;       \
    _Pragma("unroll") for (int m_ = 0; m_ < MF; ++m_) {                               \
        afA[m_][0] = *(const bf16x8*)(Ah_ + rowAb[m_]);                               \
        afA[m_][1] = *(const bf16x8*)(Ah_ + (rowAb[m_] ^ 64)); } } while (0)
#define RDB(DST, B_, H_) do { const char* Bh_ = ldsB + (((B_) << 1) | (H_)) * BHB;    \
    _Pragma("unroll") for (int n_ = 0; n_ < 2; ++n_) {                                \
        DST[n_][0] = *(const bf16x8*)(Bh_ + rowBb[n_]);                               \
        DST[n_][1] = *(const bf16x8*)(Bh_ + (rowBb[n_] ^ 64)); } } while (0)
#define MM(MH, NH, BREG) do {                                                         \
    __builtin_amdgcn_s_setprio(1);                                                    \
    _Pragma("unroll") for (int m_ = 0; m_ < MF; ++m_)                                 \
        _Pragma("unroll") for (int n_ = 0; n_ < 2; ++n_) {                            \
            acc[MH][NH][m_][n_] = __builtin_amdgcn_mfma_f32_16x16x32_bf16(            \
                afA[m_][0], BREG[n_][0], acc[MH][NH][m_][n_], 0, 0, 0);               \
            acc[MH][NH][m_][n_] = __builtin_amdgcn_mfma_f32_16x16x32_bf16(            \
                afA[m_][1], BREG[n_][1], acc[MH][NH][m_][n_], 0, 0, 0); }             \
    __builtin_amdgcn_s_setprio(0); } while (0)
#define VMW do { if constexpr (BN == 256)                                             \
                     asm volatile("s_waitcnt vmcnt(4)" ::: "memory");                 \
                 else asm volatile("s_waitcnt vmcnt(3)" ::: "memory"); } while (0)
#define FEN asm volatile("" ::: "memory")
#define ENDP do { asm volatile("" ::: "memory");                                      \
                  __builtin_amdgcn_s_barrier(); } while (0)

    // ---- prologue: 6 slots (buf0 full + buf1 half0); gate leaves buf1-half0 in flight
    issueA(0, 0, 0);  issueB(0, 0, 0);
    issueA(1, 0, 0);  issueB(1, 0, 0);
    issueA(0, 1, 64); issueB(0, 1, 64);
    VMW;
    __builtin_amdgcn_s_barrier();

    // ---- PIPE=2, 2 barriers/iter (p3-end, p7-end) ----
    RDA(0, 0); RDB(bf0, 0, 0);
    for (int J = 0; J < NITER; ++J) {
        const unsigned kc = ((unsigned)J << 7);
        // region [p0..p3]
        issueA(1, 1, kc + 64); RDB(bf1, 0, 1); MM(0, 0, bf0);
        issueB(1, 1, kc + 64); MM(0, 1, bf1); RDA(0, 1); FEN;
        issueA(0, 0, kc + 128); MM(1, 1, bf1);
        issueB(0, 0, kc + 128); MM(1, 0, bf0); VMW; RDA(1, 0); RDB(bf0, 1, 0); ENDP;
        // region [p4..p7]
        issueA(1, 0, kc + 128); RDB(bf1, 1, 1); MM(0, 0, bf0);
        issueB(1, 0, kc + 128); MM(0, 1, bf1); RDA(1, 1); FEN;
        issueA(0, 1, kc + 192); MM(1, 1, bf1);
        issueB(0, 1, kc + 192); MM(1, 0, bf0); VMW; RDA(0, 0); RDB(bf0, 0, 0); ENDP;
    }
#undef RDA
#undef RDB
#undef MM
#undef VMW
#undef FEN
#undef ENDP

    const int colc = l & 15, rb = (l >> 4) * 4;
    #pragma unroll
    for (int mh = 0; mh < 2; ++mh)
    #pragma unroll
    for (int nh = 0; nh < 2; ++nh)
    #pragma unroll
    for (int m = 0; m < MF; ++m)
    #pragma unroll
    for (int n = 0; n < 2; ++n) {
        int c = n0 + nh * (BN / 2) + wc * 32 + n * 16 + colc;
        int r0r = m0 + mh * 128 + wr * MROW + m * 16 + rb;
        if (EPI == 0) {
            u16* Cb = (u16*)Cv;
            #pragma unroll
            for (int j = 0; j < 4; ++j)
                Cb[(size_t)(r0r + j) * ND + c] = f2bf(acc[mh][nh][m][n][j]);
        } else {
            float* Cf = (float*)Cv;
            float bv = bias[c];
            #pragma unroll
            for (int j = 0; j < 4; ++j)
                Cf[(size_t)(r0r + j) * ND + c] = (acc[mh][nh][m][n][j] + bv) * 0.125f;
        }
    }
}

extern "C" void kernel_launch(void* const* d_in, const int* in_sizes, int n_in,
                              void* d_out, int out_size, void* d_ws, size_t ws_size,
                              hipStream_t stream) {
    const float* hin  = (const float*)d_in[0];
    const float* S1s  = (const float*)d_in[1];
    const float* S2s  = (const float*)d_in[2];
    const float* U1s  = (const float*)d_in[3];
    const float* U2s  = (const float*)d_in[4];
    const float* bias = (const float*)d_in[5];
    float* out = (float*)d_out;

    // ws: [hinbf][Wx (W1T then W2T)][abf], each padded 512B for the last
    // iteration's prefetch overread (<=256B past the K extent).
    const size_t SZ_HIN = (size_t)BB * DIN * 2 + 512;
    const size_t SZ_W   = (size_t)RK * DIN * 2 + 512;
    const size_t SZ_A   = (size_t)BB * RK * 2 + 512;
    if (ws_size < SZ_HIN + SZ_W + SZ_A) return;
    u16* hinbf = (u16*)d_ws;
    u16* Wx    = (u16*)((char*)d_ws + SZ_HIN);
    u16* abf   = (u16*)((char*)d_ws + SZ_HIN + SZ_W);

    (void)hipFuncSetAttribute(reinterpret_cast<const void*>(&gemm8<128, 4, 0, RK, DIN>),
                              hipFuncAttributeMaxDynamicSharedMemorySize, 98304);
    (void)hipFuncSetAttribute(reinterpret_cast<const void*>(&gemm8<256, 2, 1, DOUT, RK>),
                              hipFuncAttributeMaxDynamicSharedMemorySize, 131072);

    // 1) pack W1T [RK][DIN]; hin -> bf16
    pack_w1t<<<64 * 4 * 8, 256, 0, stream>>>(S1s, U2s, Wx);
    cvt_f32_bf16<<<(BB * DIN / 8) / 256, 256, 0, stream>>>(hin, hinbf, BB * DIN / 8);
    // 2) a[b][r] = sum_d hin[b][d] * W1T[r][d]   (M=4096, N=2048, K=4096)
    gemm8<128, 4, 0, RK, DIN><<<256, 512, 98304, stream>>>(hinbf, Wx, abf, nullptr);
    // 3) pack W2T [DOUT][RK] (reuses Wx after gemm1)
    pack_w2t<<<64 * 4 * 8, 256, 0, stream>>>(U1s, S2s, Wx);
    // 4) out = (a @ W2T^T + bias) / 8   (M=4096, N=4096, K=2048)
    gemm8<256, 2, 1, DOUT, RK><<<256, 512, 131072, stream>>>(abf, Wx, out, bias);
}